// Round 1
// 248.532 us; speedup vs baseline: 1.0381x; 1.0381x over previous
//
#include <hip/hip_runtime.h>

typedef float  f4v  __attribute__((ext_vector_type(4)));
typedef __bf16 bf8v __attribute__((ext_vector_type(8)));
typedef unsigned int u32x2 __attribute__((ext_vector_type(2)));
typedef unsigned int u32x4 __attribute__((ext_vector_type(4)));
typedef unsigned short u16;

#define MFMA(a,b,c) __builtin_amdgcn_mfma_f32_16x16x32_bf16((a),(b),(c),0,0,0)
#define HW_N 16384

// round-to-nearest-even fp32 -> bf16 bits (finite inputs)
__device__ __forceinline__ u16 bf_rne(float x){
  unsigned u = __float_as_uint(x);
  u += 0x7fffu + ((u >> 16) & 1u);
  return (u16)(u >> 16);
}

// ---------------- K_A: folded weights -------------------------------------
__global__ void k_weights(const float* __restrict__ w1, const float* __restrict__ b1,
                          const float* __restrict__ w2, const float* __restrict__ b2,
                          const float* __restrict__ w3, const float* __restrict__ b3,
                          const float* __restrict__ w4, const float* __restrict__ b4,
                          float* __restrict__ Wq, float* __restrict__ WkT,
                          float* __restrict__ Wv, float* __restrict__ bq,
                          float* __restrict__ bk, float* __restrict__ bv)
{
  const int blk = blockIdx.x, t = threadIdx.x;
  if (blk == 96){
    float aq = 0.f, ak = 0.f, av = 0.f;
    for (int j = 0; j < 256; ++j){
      const float bb = b1[j];
      aq += w2[t*256 + j] * bb;
      ak += w3[t*256 + j] * bb;
      av += w4[t*256 + j] * bb;
    }
    bq[t] = aq + b2[t];
    bk[t] = ak + b3[t];
    bv[t] = av + b4[t];
    return;
  }
  for (int i = 0; i < 8; ++i){
    const int e   = blk*2048 + i*256 + t;
    const int mat = e >> 16;
    const int c   = (e >> 8) & 255;
    const int col = e & 255;
    const float* wsrc = (mat == 0) ? w2 : ((mat == 1) ? w3 : w4);
    float acc = 0.f;
    for (int j = 0; j < 256; ++j) acc += wsrc[c*256 + j] * w1[j*256 + col];
    if      (mat == 0) Wq [c*256 + col] = acc;
    else if (mat == 1) WkT[col*256 + c] = acc;
    else               Wv [c*256 + col] = acc;
  }
}

// ---------------- K_B: Gram G = x x^T (split-bf16, 3 MFMA passes) ----------
__global__ __launch_bounds__(512, 2) void k_gram(
    const float* __restrict__ xa, const float* __restrict__ xb,
    float* __restrict__ Gpart, float* __restrict__ spart)
{
  __shared__ u16 hbuf[2][256*64];
  __shared__ u16 lbuf[2][256*64];
  const int blk = blockIdx.x;
  const int b = blk >> 5, half = (blk >> 4) & 1, chunk = blk & 15;
  const int t = threadIdx.x;
  const int lane = t & 63, w = t >> 6;
  const int wr = w >> 1, wc = w & 1;
  const int c4 = t & 15, crow = t >> 4;

  const float* rowp[8];
#pragma unroll
  for (int p = 0; p < 8; ++p){
    const int c = crow + 32*p;
    const float* base = (c < 128) ? (xa + (size_t)(b*128 + c) * HW_N)
                                  : (xb + (size_t)(b*128 + (c-128)) * HW_N);
    rowp[p] = base + c4*4;
  }

  float ssum[8];
#pragma unroll
  for (int p = 0; p < 8; ++p) ssum[p] = 0.f;

  const f4v vzero = {0.f, 0.f, 0.f, 0.f};
  f4v acc[4][4];
#pragma unroll
  for (int i = 0; i < 4; ++i)
#pragma unroll
    for (int j = 0; j < 4; ++j) acc[i][j] = vzero;

  f4v ld[8];
  auto issue = [&](int s){
    const int n0 = chunk*1024 + s*64;
#pragma unroll
    for (int p = 0; p < 8; ++p) ld[p] = *(const f4v*)(rowp[p] + n0);
  };
  auto wbuf = [&](int bi){
#pragma unroll
    for (int p = 0; p < 8; ++p){
      const int c = crow + 32*p;
      const f4v v = ld[p];
      ssum[p] += (v[0] + v[1]) + (v[2] + v[3]);
      u16 h[4], l[4];
#pragma unroll
      for (int i = 0; i < 4; ++i){
        const float x = v[i];
        const u16 hb = bf_rne(x);
        const float hf = __uint_as_float(((unsigned)hb) << 16);
        h[i] = hb; l[i] = bf_rne(x - hf);
      }
      u32x2 hp, lp;
      hp[0] = (unsigned)h[0] | ((unsigned)h[1] << 16);
      hp[1] = (unsigned)h[2] | ((unsigned)h[3] << 16);
      lp[0] = (unsigned)l[0] | ((unsigned)l[1] << 16);
      lp[1] = (unsigned)l[2] | ((unsigned)l[3] << 16);
      const int off = c*64 + (((c4 >> 1) ^ (c & 7)) * 8) + (c4 & 1) * 4;
      *(u32x2*)&hbuf[bi][off] = hp;
      *(u32x2*)&lbuf[bi][off] = lp;
    }
  };
  auto mstep = [&](int bi){
#pragma unroll
    for (int kk = 0; kk < 2; ++kk){
      bf8v ah[4], al[4], bh[4], bl[4];
#pragma unroll
      for (int f = 0; f < 4; ++f){
        const int so = kk*4 + (lane >> 4);
        const int r  = wr*64 + f*16 + (lane & 15);
        const int oa = r*64 + ((so ^ (r & 7)) * 8);
        ah[f] = *(const bf8v*)&hbuf[bi][oa];
        al[f] = *(const bf8v*)&lbuf[bi][oa];
        const int rc = 128*half + wc*64 + f*16 + (lane & 15);
        const int ob = rc*64 + ((so ^ (rc & 7)) * 8);
        bh[f] = *(const bf8v*)&hbuf[bi][ob];
        bl[f] = *(const bf8v*)&lbuf[bi][ob];
      }
#pragma unroll
      for (int i = 0; i < 4; ++i)
#pragma unroll
        for (int j = 0; j < 4; ++j){
          acc[i][j] = MFMA(ah[i], bh[j], acc[i][j]);
          acc[i][j] = MFMA(ah[i], bl[j], acc[i][j]);
          acc[i][j] = MFMA(al[i], bh[j], acc[i][j]);
        }
    }
  };

  issue(0); wbuf(0); __syncthreads();
  for (int s = 0; s < 16; ++s){
    const int cur = s & 1;
    if (s < 15) issue(s + 1);
    mstep(cur);
    if (s < 15) wbuf(cur ^ 1);
    __syncthreads();
  }

  float* gp = Gpart + (size_t)((b*2 + half)*16 + chunk) * 32768;
#pragma unroll
  for (int i = 0; i < 4; ++i)
#pragma unroll
    for (int j = 0; j < 4; ++j){
      const int row = wr*64 + i*16 + ((lane >> 4) << 2);
      const int col = wc*64 + j*16 + (lane & 15);
#pragma unroll
      for (int r2 = 0; r2 < 4; ++r2)
        gp[(row + r2)*128 + col] = acc[i][j][r2];
    }

  if (half == 0){
#pragma unroll
    for (int p = 0; p < 8; ++p){
      float v = ssum[p];
      v += __shfl_xor(v, 1);
      v += __shfl_xor(v, 2);
      v += __shfl_xor(v, 4);
      v += __shfl_xor(v, 8);
      if ((lane & 15) == 0)
        spart[(b*16 + chunk)*256 + (crow + 32*p)] = v;
    }
  }
}

// ---------------- K_C0: reduce Gram partials -------------------------------
__global__ void k_redg(const float* __restrict__ Gpart, float* __restrict__ G)
{
  for (int k = 0; k < 8; ++k){
    const int o = blockIdx.x*2048 + k*256 + threadIdx.x;
    const int b = o >> 16, r = (o >> 8) & 255, col = o & 255;
    const int half = col >> 7, cc = col & 127;
    const float* p = Gpart + (size_t)(b*2 + half)*524288 + (size_t)r*128 + cc;
    float s = 0.f;
#pragma unroll
    for (int ch = 0; ch < 16; ++ch) s += p[ch*32768];
    G[o] = s;
  }
}

// ---------------- K_C1: logits -> softmax -> M = A@Wv, cb = A@bv -----------
__device__ __forceinline__ float block_red(float v, int ismax, volatile float* red, int t){
#pragma unroll
  for (int m = 32; m; m >>= 1){
    const float o = __shfl_xor(v, m);
    v = ismax ? fmaxf(v, o) : (v + o);
  }
  if ((t & 63) == 0) red[t >> 6] = v;
  __syncthreads();
  const float r01 = ismax ? fmaxf(red[0], red[1]) : (red[0] + red[1]);
  const float r23 = ismax ? fmaxf(red[2], red[3]) : (red[2] + red[3]);
  v = ismax ? fmaxf(r01, r23) : (r01 + r23);
  __syncthreads();
  return v;
}

__global__ __launch_bounds__(256, 2) void k_attn(
    const float* __restrict__ G, const float* __restrict__ spart,
    const float* __restrict__ Wq, const float* __restrict__ WkT,
    const float* __restrict__ Wv, const float* __restrict__ bq,
    const float* __restrict__ bk, const float* __restrict__ bv,
    u16* __restrict__ Mfrag, float* __restrict__ cb)
{
  __shared__ float s_lds[256];
  __shared__ float wq_lds[4][256];
  __shared__ float t1_lds[4][256];
  __shared__ float a_lds[4][256];
  __shared__ float red[4];
  const int blk = blockIdx.x;
  const int b = blk >> 6, r0 = (blk & 63) * 4;
  const int t = threadIdx.x;

  float sv = 0.f;
#pragma unroll
  for (int ch = 0; ch < 16; ++ch) sv += spart[(b*16 + ch)*256 + t];
  s_lds[t] = sv;
#pragma unroll
  for (int ri = 0; ri < 4; ++ri) wq_lds[ri][t] = Wq[(r0 + ri)*256 + t];
  __syncthreads();

  float t1[4] = {0,0,0,0}, pv[4] = {0,0,0,0};
  const float* gb = G + (size_t)b * 65536;
  for (int k = 0; k < 256; ++k){
    const float g  = gb[k*256 + t];
    const float sk = s_lds[k];
#pragma unroll
    for (int ri = 0; ri < 4; ++ri){
      const float wqv = wq_lds[ri][k];
      t1[ri] += wqv * g;
      pv[ri] += wqv * sk;
    }
  }
#pragma unroll
  for (int ri = 0; ri < 4; ++ri) t1_lds[ri][t] = t1[ri];
  __syncthreads();

  float qk[4] = {0,0,0,0}, rd = 0.f;
  for (int n = 0; n < 256; ++n){
    const float wkt = WkT[n*256 + t];
    rd += wkt * s_lds[n];
#pragma unroll
    for (int ri = 0; ri < 4; ++ri) qk[ri] += t1_lds[ri][n] * wkt;
  }
  const float bkv = bk[t];
#pragma unroll
  for (int ri = 0; ri < 4; ++ri){
    const float bqv = bq[r0 + ri];
    qk[ri] += pv[ri]*bkv + bqv*rd + 16384.f*bqv*bkv;
  }

  float areg[4];
#pragma unroll
  for (int ri = 0; ri < 4; ++ri){
    const float m = block_red(qk[ri], 1, red, t);
    const float e = __expf(qk[ri] - m);
    const float s = block_red(e, 0, red, t);
    areg[ri] = e / s;
    a_lds[ri][t] = areg[ri];
  }
  const float bvv = bv[t];
#pragma unroll
  for (int ri = 0; ri < 4; ++ri){
    const float c = block_red(areg[ri]*bvv, 0, red, t);
    if (t == 0) cb[b*256 + r0 + ri] = c;
  }
  __syncthreads();

  float m4[4] = {0,0,0,0};
  for (int d = 0; d < 256; ++d){
    const float wv = Wv[d*256 + t];
#pragma unroll
    for (int ri = 0; ri < 4; ++ri) m4[ri] += a_lds[ri][d] * wv;
  }
  const int ks = t >> 5, lhi = (t >> 3) & 3, j = t & 7;
#pragma unroll
  for (int ri = 0; ri < 4; ++ri){
    const int o = r0 + ri;
    Mfrag[(size_t)b*65536 +
          (size_t)((((o >> 4)*8 + ks)*64) + (o & 15) + (lhi << 4))*8 + j] = bf_rne(m4[ri]);
  }
}

// ---------------- K_D: out = M @ x + cb (bf16 MFMA, memory-bound) ----------
// grid 512 = 8 batches x 64 pixel-chunks(256). block 512 (8 waves).
// Each wave owns 32 distinct output rows -> af = 64 AGPRs, no duplication.
// 32-px steps, ~126 total regs -> 2 blocks/CU so barrier drains overlap.
// 4-bit LDS slot swizzle (c>>3)^(n&15): 16 distinct 16B slots/quarter-wave.
__global__ __launch_bounds__(512, 4) void k_out(
    const float* __restrict__ xa, const float* __restrict__ xb,
    const u16* __restrict__ Mfrag, const float* __restrict__ cb,
    float* __restrict__ out)
{
  __shared__ u16 xt[2][32*256];   // [dbuf][n_local][c], XOR-swizzled, 16 KB each
  const int blk = blockIdx.x;
  const int b = blk >> 6, nchunk = blk & 63;
  const int t = threadIdx.x;
  const int lane = t & 63, w = t >> 6;   // wave w owns out rows w*32 .. w*32+31
  const int cr = t >> 1;                 // staging channel/row 0..255
  const int hf = t & 1;                  // which 16-px half this thread stages

  // A fragments: rows w*32 + f*16 -> obi = w*2+f, ks = 0..7 (64 AGPRs total)
  u32x4 af[2][8];
  const u16* mb = Mfrag + (size_t)b * 65536;
#pragma unroll
  for (int f = 0; f < 2; ++f)
#pragma unroll
    for (int ks = 0; ks < 8; ++ks)
      af[f][ks] = *(const u32x4*)(mb + (size_t)((((w*2 + f)*8 + ks)*64 + lane))*8);
#pragma unroll
  for (int f = 0; f < 2; ++f)
#pragma unroll
    for (int ks = 0; ks < 8; ++ks)
      asm volatile("" : "+a"(af[f][ks]));   // pin to AGPRs (MFMA A-operand)

  f4v cb4[2];
#pragma unroll
  for (int f = 0; f < 2; ++f)
    cb4[f] = *(const f4v*)(cb + b*256 + w*32 + f*16 + ((lane >> 4) << 2));

  const float* rowbase = (cr < 128) ? (xa + (size_t)(b*128 + cr)*HW_N)
                                    : (xb + (size_t)(b*128 + (cr-128))*HW_N);
  const float* rp = rowbase + hf*16;

  f4v ld[4];
  auto issue = [&](int s){
    const int n0 = nchunk*256 + s*32;
#pragma unroll
    for (int q = 0; q < 4; ++q) ld[q] = *(const f4v*)(rp + n0 + q*4);
  };
  auto cvtwrite = [&](int bi){
#pragma unroll
    for (int q = 0; q < 4; ++q){
      const f4v v = ld[q];
#pragma unroll
      for (int i = 0; i < 4; ++i){
        const int n = hf*16 + q*4 + i;     // 0..31 local px
        xt[bi][n*256 + (((cr >> 3) ^ (n & 15))*8) + (cr & 7)] = bf_rne(v[i]);
      }
    }
  };

  const f4v vzero = {0.f, 0.f, 0.f, 0.f};
  float* outp = out + (size_t)b*256*HW_N;

  issue(0);
  cvtwrite(0);
  __syncthreads();

  for (int s = 0; s < 8; ++s){
    const int cur = s & 1;
    if (s < 7) issue(s + 1);

    const int n0 = nchunk*256 + s*32;
    f4v acc[2][2];
#pragma unroll
    for (int f = 0; f < 2; ++f){ acc[f][0] = vzero; acc[f][1] = vzero; }

#pragma unroll
    for (int ks = 0; ks < 8; ++ks){
      bf8v bfr[2];
#pragma unroll
      for (int g = 0; g < 2; ++g){
        const int n  = g*16 + (lane & 15);
        const int so = ks*4 + (lane >> 4);
        bfr[g] = *(const bf8v*)&xt[cur][n*256 + ((so ^ (n & 15))*8)];
      }
#pragma unroll
      for (int f = 0; f < 2; ++f){
        acc[f][0] = MFMA(__builtin_bit_cast(bf8v, af[f][ks]), bfr[0], acc[f][0]);
        acc[f][1] = MFMA(__builtin_bit_cast(bf8v, af[f][ks]), bfr[1], acc[f][1]);
      }
    }

#pragma unroll
    for (int f = 0; f < 2; ++f)
#pragma unroll
      for (int g = 0; g < 2; ++g){
        const int row = w*32 + f*16 + ((lane >> 4) << 2);
        const int col = n0 + g*16 + (lane & 15);
#pragma unroll
        for (int r2 = 0; r2 < 4; ++r2)
          outp[(size_t)(row + r2)*HW_N + col] = acc[f][g][r2] + cb4[f][r2];
      }

    if (s < 7) cvtwrite(cur ^ 1);
    __syncthreads();
  }
}

// ---------------- launcher -------------------------------------------------
extern "C" void kernel_launch(void* const* d_in, const int* in_sizes, int n_in,
                              void* d_out, int out_size, void* d_ws, size_t ws_size,
                              hipStream_t stream)
{
  const float* xa = (const float*)d_in[0];
  const float* xb = (const float*)d_in[1];
  const float* w1 = (const float*)d_in[2];
  const float* b1 = (const float*)d_in[3];
  const float* w2 = (const float*)d_in[4];
  const float* b2 = (const float*)d_in[5];
  const float* w3 = (const float*)d_in[6];
  const float* b3 = (const float*)d_in[7];
  const float* w4 = (const float*)d_in[8];
  const float* b4 = (const float*)d_in[9];
  float* out = (float*)d_out;
  char*  ws  = (char*)d_ws;

  float* Gpart = (float*)(ws + 0);          // 33,554,432 B
  float* G     = (float*)(ws + 33554432);   //  2,097,152 B
  float* spart = (float*)(ws + 35651584);   //    131,072 B
  float* Wq    = (float*)(ws + 35782656);   //    262,144 B
  float* WkT   = (float*)(ws + 36044800);   //    262,144 B
  float* Wv    = (float*)(ws + 36306944);   //    262,144 B
  float* bq    = (float*)(ws + 36569088);   //      1,024 B
  float* bk    = (float*)(ws + 36570112);
  float* bv    = (float*)(ws + 36571136);
  u16*   Mfrag = (u16*)  (ws + 36572160);   //  1,048,576 B
  float* cb    = (float*)(ws + 37620736);   //      8,192 B

  hipLaunchKernelGGL(k_weights, dim3(97),  dim3(256), 0, stream,
                     w1,b1,w2,b2,w3,b3,w4,b4, Wq,WkT,Wv,bq,bk,bv);
  hipLaunchKernelGGL(k_gram,    dim3(256), dim3(512), 0, stream, xa, xb, Gpart, spart);
  hipLaunchKernelGGL(k_redg,    dim3(256), dim3(256), 0, stream, Gpart, G);
  hipLaunchKernelGGL(k_attn,    dim3(512), dim3(256), 0, stream,
                     G, spart, Wq, WkT, Wv, bq, bk, bv, Mfrag, cb);
  hipLaunchKernelGGL(k_out,     dim3(512), dim3(512), 0, stream, xa, xb, Mfrag, cb, out);
}